// Round 1
// baseline (15896.126 us; speedup 1.0000x reference)
//
#include <hip/hip_runtime.h>
#include <stdint.h>

// ConvLSTMDecoder: B=64 T=48 C_IN=64 HID=128 H=W=15 K=3 OUT=128
// Strategy: per (layer,t) one fused im2col-GEMM kernel, split-bf16 MFMA
// (hi/lo decomposition, 3x mfma_f32_16x16x32_bf16) for fp32-grade accuracy,
// gates fused in epilogue via permuted weight layout.

typedef unsigned int u32;
typedef __attribute__((ext_vector_type(8))) short short8;   // 8 bf16 = 4 VGPR
typedef __attribute__((ext_vector_type(4))) float f32x4;

#define NB   64
#define NT   48
#define NCX  64
#define NHID 128
#define NPIX 225
#define MTOT (NB*NPIX)      // 14400
#define MT_TILES 113        // ceil(14400/128)

__device__ __forceinline__ u32 bf16_rne(u32 u) {
  return (u + 0x7fffu + ((u >> 16) & 1u)) >> 16;
}
// pack f32 -> (lo16<<16)|hi16 split pair: f ~= bf16(hi) + bf16(lo), err ~2^-17
__device__ __forceinline__ u32 packsplit(float f) {
  u32 u  = __float_as_uint(f);
  u32 hi = bf16_rne(u);
  float fhi = __uint_as_float(hi << 16);
  u32 lo = bf16_rne(__float_as_uint(f - fhi));
  return (lo << 16) | hi;
}
// two packed pairs -> (hi1,hi0) word and (lo1,lo0) word
__device__ __forceinline__ void splitpair(u32 p0, u32 p1, u32& hw, u32& lw) {
  hw = __builtin_amdgcn_perm(p1, p0, 0x05040100u);
  lw = __builtin_amdgcn_perm(p1, p0, 0x07060302u);
}
__device__ __forceinline__ float sigmoidf_(float x) { return 1.f / (1.f + __expf(-x)); }
__device__ __forceinline__ float tanhf_(float x) {
  float e = __expf(-2.f * fabsf(x));
  float t = (1.f - e) / (1.f + e);
  return copysignf(t, x);
}

// ---------------- weight/bias prep: permute + split ----------------
// q = (hid>>4)*64 + gate*16 + (hid&15);  k' = r*CIN + ci  (r = kh*3+kw)
__global__ void prep_kernel(const float* __restrict__ W0, const float* __restrict__ b0,
                            const float* __restrict__ W1, const float* __restrict__ b1,
                            u32* __restrict__ Wp0, u32* __restrict__ Wp1,
                            float* __restrict__ bp) {
  const int n0 = 512 * 1728, n1 = 512 * 2304;
  for (int idx = blockIdx.x * blockDim.x + threadIdx.x; idx < n0 + n1 + 1024;
       idx += gridDim.x * blockDim.x) {
    if (idx < n0) {
      int q = idx / 1728, k = idx - q * 1728;
      int r = k / 192, ci = k - r * 192;
      int hid = ((q >> 6) << 4) | (q & 15), gate = (q >> 4) & 3;
      int co = gate * 128 + hid;
      Wp0[idx] = packsplit(W0[co * 1728 + ci * 9 + r]);
    } else if (idx < n0 + n1) {
      int e = idx - n0;
      int q = e / 2304, k = e - q * 2304;
      int r = k / 256, ci = k - r * 256;
      int hid = ((q >> 6) << 4) | (q & 15), gate = (q >> 4) & 3;
      int co = gate * 128 + hid;
      Wp1[e] = packsplit(W1[co * 2304 + ci * 9 + r]);
    } else {
      int e = idx - n0 - n1;           // 0..1023
      int l = e >> 9, q = e & 511;
      int hid = ((q >> 6) << 4) | (q & 15), gate = (q >> 4) & 3;
      bp[e] = (l == 0 ? b0 : b1)[gate * 128 + hid];
    }
  }
}

// ---------------- fused ConvLSTM step ----------------
// LAYER=1: input = concat(x_t[64ch f32], h1[128ch packed]);  K=1728
// LAYER=2: input = concat(h1_t[128ch packed], h2[128ch packed]); K=2304
template <int LAYER>
__global__ __launch_bounds__(256, 2)
void step_kernel(const float* __restrict__ x, int t,
                 const u32* __restrict__ xs,      // layer2: h1 current (packed)
                 const u32* __restrict__ hprev,   // own h state prev (packed)
                 const u32* __restrict__ Wp,      // permuted split weights [512][K]
                 const float* __restrict__ bp,    // permuted bias [512]
                 float* __restrict__ c,           // own cell state f32 (in-place)
                 u32* __restrict__ hout)          // own h state new (packed)
{
  constexpr int CINL = (LAYER == 1) ? 192 : 256;
  constexpr int SUBS = CINL / 64;
  constexpr int K    = CINL * 9;
  constexpr int NK   = K / 64;

  // 64KB LDS, fragment-ready layout: [buf][kg(8)][row(128)] of uint4 (8 bf16)
  // buf: 0=A_hi 1=A_lo 2=B_hi 3=B_lo
  __shared__ uint4 lds[4096];

  const int tid  = threadIdx.x;
  const int mt   = blockIdx.x, nt = blockIdx.y;
  const int lane = tid & 63;
  const int w    = tid >> 6;
  const int wave_m = (w >> 1) * 64, wave_n = (w & 1) * 64;

  // staging coords: thread covers row srow for 4 kgroups {khalf, khalf+2, ...}
  const int srow  = tid & 127;
  const int khalf = tid >> 7;
  const int m_s   = mt * 128 + srow;
  const bool m_ok = (m_s < MTOT);
  const int bs  = m_ok ? (m_s / 225) : 0;
  const int ps  = m_s - bs * 225;
  const int phs = ps / 15, pws = ps - phs * 15;
  const u32* wrow = Wp + (size_t)(nt * 128 + srow) * K;

  f32x4 acc[4][4];
  #pragma unroll
  for (int i = 0; i < 4; ++i)
    #pragma unroll
    for (int j = 0; j < 4; ++j) acc[i][j] = (f32x4){0.f, 0.f, 0.f, 0.f};

  for (int kb = 0; kb < NK; ++kb) {
    const int r = kb / SUBS, sub = kb - r * SUBS;
    const int ih = phs + (r / 3) - 1, iw = pws + (r % 3) - 1;
    const bool valid = m_ok && ((unsigned)ih < 15u) && ((unsigned)iw < 15u);
    const int pix = ih * 15 + iw;

    // ---- stage A (input tile, 128 rows x 64 k), hi/lo split ----
    #pragma unroll
    for (int i = 0; i < 4; ++i) {
      const int kg = khalf + 2 * i;
      u32 hw[4], lw[4];
      if (LAYER == 1 && sub == 0) {           // x part: f32, split on the fly
        const float* src = x + (((size_t)bs * NT + t) * NCX + kg * 8) * NPIX + pix;
        #pragma unroll
        for (int jj = 0; jj < 4; ++jj) {
          float f0 = valid ? src[(2 * jj) * NPIX] : 0.f;
          float f1 = valid ? src[(2 * jj + 1) * NPIX] : 0.f;
          splitpair(packsplit(f0), packsplit(f1), hw[jj], lw[jj]);
        }
      } else {                                 // packed u32 states
        const u32* src; int ci0;
        if (LAYER == 1) { src = hprev; ci0 = (sub - 1) * 64; }
        else { if (sub < 2) { src = xs; ci0 = sub * 64; }
               else        { src = hprev; ci0 = (sub - 2) * 64; } }
        const u32* sp = src + ((size_t)bs * NHID + ci0 + kg * 8) * NPIX + pix;
        #pragma unroll
        for (int jj = 0; jj < 4; ++jj) {
          u32 p0 = valid ? sp[(2 * jj) * NPIX] : 0u;
          u32 p1 = valid ? sp[(2 * jj + 1) * NPIX] : 0u;
          splitpair(p0, p1, hw[jj], lw[jj]);
        }
      }
      lds[0 * 1024 + kg * 128 + srow] = make_uint4(hw[0], hw[1], hw[2], hw[3]);
      lds[1 * 1024 + kg * 128 + srow] = make_uint4(lw[0], lw[1], lw[2], lw[3]);
    }
    // ---- stage B (weights, 128 q x 64 k), pre-split packed ----
    #pragma unroll
    for (int i = 0; i < 4; ++i) {
      const int kg = khalf + 2 * i;
      const u32* wp8 = wrow + kb * 64 + kg * 8;
      uint4 pa = *(const uint4*)(wp8);
      uint4 pb = *(const uint4*)(wp8 + 4);
      uint4 hv, lv;
      splitpair(pa.x, pa.y, hv.x, lv.x);
      splitpair(pa.z, pa.w, hv.y, lv.y);
      splitpair(pb.x, pb.y, hv.z, lv.z);
      splitpair(pb.z, pb.w, hv.w, lv.w);
      lds[2 * 1024 + kg * 128 + srow] = hv;
      lds[3 * 1024 + kg * 128 + srow] = lv;
    }
    __syncthreads();

    // ---- MFMA: 2 x K32 blocks, 4x4 frags, 3 mfma per pair (split-bf16) ----
    #pragma unroll
    for (int kk = 0; kk < 2; ++kk) {
      const int kgc  = kk * 4 + (lane >> 4);
      const int arow = wave_m + (lane & 15);
      const int brow = wave_n + (lane & 15);
      short8 ah[4], al[4], bh[4], bl[4];
      #pragma unroll
      for (int mb = 0; mb < 4; ++mb) {
        ah[mb] = *(const short8*)&lds[0 * 1024 + kgc * 128 + arow + mb * 16];
        al[mb] = *(const short8*)&lds[1 * 1024 + kgc * 128 + arow + mb * 16];
      }
      #pragma unroll
      for (int nb = 0; nb < 4; ++nb) {
        bh[nb] = *(const short8*)&lds[2 * 1024 + kgc * 128 + brow + nb * 16];
        bl[nb] = *(const short8*)&lds[3 * 1024 + kgc * 128 + brow + nb * 16];
      }
      #pragma unroll
      for (int mb = 0; mb < 4; ++mb)
        #pragma unroll
        for (int nb = 0; nb < 4; ++nb) {
          acc[mb][nb] = __builtin_amdgcn_mfma_f32_16x16x32_bf16(ah[mb], bh[nb], acc[mb][nb], 0, 0, 0);
          acc[mb][nb] = __builtin_amdgcn_mfma_f32_16x16x32_bf16(al[mb], bh[nb], acc[mb][nb], 0, 0, 0);
          acc[mb][nb] = __builtin_amdgcn_mfma_f32_16x16x32_bf16(ah[mb], bl[nb], acc[mb][nb], 0, 0, 0);
        }
    }
    __syncthreads();
  }

  // ---- epilogue: gates, c/h update. nb == gate (0=i 1=f 2=o 3=g) ----
  const int colq = nt * 128 + wave_n;
  const int hid  = ((colq >> 6) << 4) + (lane & 15);
  const float bi = bp[colq +      (lane & 15)];
  const float bf = bp[colq + 16 + (lane & 15)];
  const float bo = bp[colq + 32 + (lane & 15)];
  const float bg = bp[colq + 48 + (lane & 15)];
  #pragma unroll
  for (int mb = 0; mb < 4; ++mb) {
    #pragma unroll
    for (int rr = 0; rr < 4; ++rr) {
      int m = mt * 128 + wave_m + mb * 16 + ((lane >> 4) << 2) + rr;
      if (m < MTOT) {
        int b = m / 225, p = m - b * 225;
        float gi = sigmoidf_(acc[mb][0][rr] + bi);
        float gf = sigmoidf_(acc[mb][1][rr] + bf);
        float go = sigmoidf_(acc[mb][2][rr] + bo);
        float gg = tanhf_   (acc[mb][3][rr] + bg);
        size_t idx = ((size_t)b * NHID + hid) * NPIX + p;
        float cn = gf * c[idx] + gi * gg;
        c[idx] = cn;
        float h = go * tanhf_(cn);
        hout[idx] = packsplit(h);
      }
    }
  }
}

// ---------------- final dense: feat[64][28800] @ Wd[28800][128] + bd ----------------
__global__ void dense_partial(const u32* __restrict__ h2, const float* __restrict__ Wd,
                              float* __restrict__ part) {
  int b = blockIdx.x, ks = blockIdx.y, n = threadIdx.x;
  const u32* f = h2 + (size_t)b * 28800 + ks * 3600;
  const float* wdp = Wd + (size_t)ks * 3600 * 128 + n;
  float s = 0.f;
  for (int k = 0; k < 3600; ++k) {
    u32 u = f[k];
    float xv = __uint_as_float(u << 16) + __uint_as_float(u & 0xffff0000u);
    s = fmaf(xv, wdp[(size_t)k * 128], s);
  }
  part[(b * 8 + ks) * 128 + n] = s;
}
__global__ void dense_reduce(const float* __restrict__ part, const float* __restrict__ bd,
                             float* __restrict__ out) {
  int b = blockIdx.x, n = threadIdx.x;
  float s = bd[n];
  #pragma unroll
  for (int ks = 0; ks < 8; ++ks) s += part[(b * 8 + ks) * 128 + n];
  out[b * 128 + n] = s;
}

extern "C" void kernel_launch(void* const* d_in, const int* in_sizes, int n_in,
                              void* d_out, int out_size, void* d_ws, size_t ws_size,
                              hipStream_t stream) {
  const float* x  = (const float*)d_in[0];
  const float* W0 = (const float*)d_in[1];
  const float* b0 = (const float*)d_in[2];
  const float* W1 = (const float*)d_in[3];
  const float* b1 = (const float*)d_in[4];
  const float* Wd = (const float*)d_in[5];
  const float* bd = (const float*)d_in[6];

  const size_t SE = 1843200;          // state elements (64*128*225)
  u32*   h1s0 = (u32*)d_ws;
  u32*   h2s0 = h1s0 + SE;
  float* c1   = (float*)(h2s0 + SE);
  float* c2   = c1 + SE;
  u32*   h1s1 = (u32*)(c2 + SE);
  u32*   h2s1 = h1s1 + SE;
  u32*   Wp0  = h2s1 + SE;            // 512*1728
  u32*   Wp1  = Wp0 + 512 * 1728;     // 512*2304
  float* bp   = (float*)(Wp1 + 512 * 2304);  // 1024
  float* part = bp + 1024;            // 64*8*128
  const size_t need = (SE * 6 + 512 * 1728 + 512 * 2304 + 1024 + 64 * 8 * 128) * 4;
  if (ws_size < need) return;

  // zero h1s0, h2s0, c1, c2 (contiguous leading region)
  hipMemsetAsync(d_ws, 0, SE * 4 * 4, stream);
  prep_kernel<<<2048, 256, 0, stream>>>(W0, b0, W1, b1, Wp0, Wp1, bp);

  for (int t = 0; t < NT; ++t) {
    u32* h1p = (t & 1) ? h1s1 : h1s0;
    u32* h1c = (t & 1) ? h1s0 : h1s1;
    u32* h2p = (t & 1) ? h2s1 : h2s0;
    u32* h2c = (t & 1) ? h2s0 : h2s1;
    step_kernel<1><<<dim3(MT_TILES, 4), 256, 0, stream>>>(x, t, nullptr, h1p, Wp0, bp, c1, h1c);
    step_kernel<2><<<dim3(MT_TILES, 4), 256, 0, stream>>>(nullptr, 0, h1c, h2p, Wp1, bp + 512, c2, h2c);
  }
  // t=47 odd -> final h2 in h2s0
  dense_partial<<<dim3(64, 8), 128, 0, stream>>>(h2s0, Wd, part);
  dense_reduce<<<64, 128, 0, stream>>>(part, bd, (float*)d_out);
}

// Round 3
// 11603.482 us; speedup vs baseline: 1.3699x; 1.3699x over previous
//
#include <hip/hip_runtime.h>
#include <stdint.h>

// ConvLSTMDecoder: B=64 T=48 C_IN=64 HID=128 H=W=15 K=3 OUT=128
// R3 == R2 resubmission (R2 bench died at container level, not kernel level):
// paired-layer launches (L2(t) || L1(t+1)), NHWC hi/lo split state planes,
// global_load_lds staging from pre-built weight LDS images, XCD-chunked swizzle.

typedef unsigned int u32;
typedef unsigned short u16;
typedef __attribute__((ext_vector_type(8))) short short8;   // 8 bf16
typedef __attribute__((ext_vector_type(4))) float f32x4;

#define NB   64
#define NT   48
#define NCX  64
#define NHID 128
#define NPIX 225
#define MTOT (NB*NPIX)      // 14400
#define MT_TILES 113
#define NK1  27             // K=1728 / 64
#define NK2  36             // K=2304 / 64
#define L1IMG (4*NK1*2*8192)   // bf16 elems of layer1 weight images
#define L2IMG (4*NK2*2*8192)

__device__ __forceinline__ u32 bf16_rne(u32 u) {
  return (u + 0x7fffu + ((u >> 16) & 1u)) >> 16;
}
__device__ __forceinline__ float bf2f(u16 h) { return __uint_as_float(((u32)h) << 16); }
__device__ __forceinline__ void split2(float f, u32& hi, u32& lo) {
  u32 u = __float_as_uint(f);
  hi = bf16_rne(u);
  lo = bf16_rne(__float_as_uint(f - __uint_as_float(hi << 16)));
}
__device__ __forceinline__ u32 packsplit(float f) { u32 h, l; split2(f, h, l); return (l << 16) | h; }
__device__ __forceinline__ void splitpair(u32 p0, u32 p1, u32& hw, u32& lw) {
  hw = __builtin_amdgcn_perm(p1, p0, 0x05040100u);
  lw = __builtin_amdgcn_perm(p1, p0, 0x07060302u);
}
__device__ __forceinline__ float sigmoidf_(float x) { return 1.f / (1.f + __expf(-x)); }
__device__ __forceinline__ float tanhf_(float x) {
  float e = __expf(-2.f * fabsf(x));
  return copysignf((1.f - e) / (1.f + e), x);
}
__device__ __forceinline__ void gl_lds16(const void* g, void* l) {
  __builtin_amdgcn_global_load_lds(
      (const __attribute__((address_space(1))) u32*)(g),
      (__attribute__((address_space(3))) u32*)(l), 16, 0, 0);
}

// ---------------- prep: weight LDS images (split + permuted) + bias ----------------
// image element e -> [img = ntkb*2+hl][kg(8)][qrow(128)][j(8)] bf16
// q = nt*128+qrow; hid=((q>>6)<<4)|(q&15); gate=(q>>4)&3; co=gate*128+hid
// k = kb*64+kg*8+j; r=k/CINL; ci=k%CINL;  W element = W[co][ci][r]
__global__ void prep_kernel(const float* __restrict__ W0, const float* __restrict__ b0,
                            const float* __restrict__ W1, const float* __restrict__ b1,
                            u16* __restrict__ Wi1, u16* __restrict__ Wi2,
                            float* __restrict__ bp) {
  const int total = L1IMG + L2IMG + 1024;
  for (int idx = blockIdx.x * blockDim.x + threadIdx.x; idx < total;
       idx += gridDim.x * blockDim.x) {
    if (idx < L1IMG + L2IMG) {
      const int layer2 = idx >= L1IMG;
      const int e = layer2 ? idx - L1IMG : idx;
      const int NK = layer2 ? NK2 : NK1;
      const int CINL = layer2 ? 256 : 192;
      const float* W = layer2 ? W1 : W0;
      const int img = e >> 13, o = e & 8191;
      const int hl = img & 1, ntkb = img >> 1;
      const int nt = ntkb / NK, kb = ntkb - nt * NK;
      const int kg = o >> 10, rem = o & 1023, qrow = rem >> 3, j = rem & 7;
      const int q = nt * 128 + qrow;
      const int hid = ((q >> 6) << 4) | (q & 15), gate = (q >> 4) & 3;
      const int co = gate * 128 + hid;
      const int k = kb * 64 + kg * 8 + j;
      const int r = k / CINL, ci = k - r * CINL;
      const float wv = W[(size_t)co * (CINL * 9) + ci * 9 + r];
      u32 hi, lo; split2(wv, hi, lo);
      (layer2 ? Wi2 : Wi1)[e] = (u16)(hl ? lo : hi);
    } else {
      const int e2 = idx - (L1IMG + L2IMG);
      const int l = e2 >> 9, q = e2 & 511;
      const int hid = ((q >> 6) << 4) | (q & 15), gate = (q >> 4) & 3;
      bp[e2] = (l == 0 ? b0 : b1)[gate * 128 + hid];
    }
  }
}

// ---------------- fused ConvLSTM step body ----------------
// States: NHWC hi/lo bf16 planes S[b][pix][256]; ch[0:128)=h1, ch[128:256)=h2.
// LDS 64KB: A_hi[0,16K) A_lo[16K,32K) B_hi[32K,48K) B_lo[48K,64K), each
// [kg(8)][row(128)][16B] (fragment-ready, conflict-free — R1 measured 0).
template <int LAYER>
__device__ __forceinline__ void step_body(
    uint4* lds, int mt, int nt,
    const float* __restrict__ x, int t,
    const u16* __restrict__ Shr, const u16* __restrict__ Slr,
    u16* __restrict__ Shw, u16* __restrict__ Slw,
    const u16* __restrict__ Wimg, const float* __restrict__ bp,
    float* __restrict__ c, const u16* __restrict__ zp) {
  constexpr int SUBS = (LAYER == 1) ? 3 : 4;
  constexpr int NK   = (LAYER == 1) ? NK1 : NK2;

  const int tid = threadIdx.x;
  const int lane = tid & 63, w = tid >> 6;
  const int wave_m = (w >> 1) * 64, wave_n = (w & 1) * 64;
  char* ldsb = (char*)lds;

  // fast-path A coords: i=0..3 -> segment s=w*4+i, kg=s>>1, row=(s&1)*64+lane
  int pbv[4], phv[4], pwv[4], kgv[4]; bool mokv[4];
  #pragma unroll
  for (int i = 0; i < 4; ++i) {
    const int s = w * 4 + i;
    kgv[i] = s >> 1;
    const int row = (s & 1) * 64 + lane;
    const int m = mt * 128 + row;
    mokv[i] = m < MTOT;
    const int mm = mokv[i] ? m : 0;
    const int b = mm / 225, p = mm - b * 225;
    pbv[i] = mm;                      // b*225+p == m
    phv[i] = p / 15; pwv[i] = p - phv[i] * 15;
  }
  // slow-path (x) coords (LAYER1 only)
  const int srow = tid & 127, khalf = tid >> 7;
  const int ms = mt * 128 + srow;
  const bool mok_s = ms < MTOT;
  const int mms = mok_s ? ms : 0;
  const int bs = mms / 225, ps = mms - bs * 225;
  const int phs = ps / 15, pws = ps - phs * 15;

  f32x4 acc[4][4];
  #pragma unroll
  for (int i = 0; i < 4; ++i)
    #pragma unroll
    for (int j = 0; j < 4; ++j) acc[i][j] = (f32x4){0.f, 0.f, 0.f, 0.f};

  int r = 0, sub = 0;
  for (int kb = 0; kb < NK; ++kb) {
    const int dr = r / 3 - 1, dc = r - (r / 3) * 3 - 1;
    const int dp = dr * 15 + dc;

    if (LAYER == 1 && sub == 0) {
      // x part: f32, split on the fly, ds_write path
      const bool valid = mok_s && ((unsigned)(phs + dr) < 15u) && ((unsigned)(pws + dc) < 15u);
      const int pix = (phs + dr) * 15 + (pws + dc);
      #pragma unroll
      for (int i = 0; i < 4; ++i) {
        const int kg = khalf + 2 * i;
        const float* src = x + (((size_t)bs * NT + t) * NCX + kg * 8) * NPIX + pix;
        u32 hw_[4], lw_[4];
        #pragma unroll
        for (int jj = 0; jj < 4; ++jj) {
          float f0 = valid ? src[(2 * jj) * NPIX] : 0.f;
          float f1 = valid ? src[(2 * jj + 1) * NPIX] : 0.f;
          splitpair(packsplit(f0), packsplit(f1), hw_[jj], lw_[jj]);
        }
        lds[0 * 1024 + kg * 128 + srow] = make_uint4(hw_[0], hw_[1], hw_[2], hw_[3]);
        lds[1 * 1024 + kg * 128 + srow] = make_uint4(lw_[0], lw_[1], lw_[2], lw_[3]);
      }
    } else {
      const int icb = (LAYER == 1 ? (sub - 1) * 128 : sub * 128);  // channel byte offset
      #pragma unroll
      for (int i = 0; i < 4; ++i) {
        const bool v = mokv[i] && ((unsigned)(phv[i] + dr) < 15u) && ((unsigned)(pwv[i] + dc) < 15u);
        const size_t off = (size_t)(pbv[i] + dp) * 512 + icb + kgv[i] * 16;
        const char* gh = v ? (const char*)Shr + off : (const char*)zp;
        const char* gl = v ? (const char*)Slr + off : (const char*)zp;
        const int so = (w * 4 + i) * 1024;
        gl_lds16(gh, ldsb + so);
        gl_lds16(gl, ldsb + 16384 + so);
      }
    }
    {  // B: linear copy from prestaged images
      const size_t wb = ((size_t)(nt * NK + kb) * 2) * 16384;
      #pragma unroll
      for (int i = 0; i < 4; ++i) {
        const int so = (w * 4 + i) * 1024;
        gl_lds16((const char*)Wimg + wb + so + lane * 16,         ldsb + 32768 + so);
        gl_lds16((const char*)Wimg + wb + 16384 + so + lane * 16, ldsb + 49152 + so);
      }
    }
    __syncthreads();

    #pragma unroll
    for (int kk = 0; kk < 2; ++kk) {
      const int kgc = kk * 4 + (lane >> 4);
      const int arow = wave_m + (lane & 15);
      const int brow = wave_n + (lane & 15);
      short8 ah[4], al[4], bh[4], bl[4];
      #pragma unroll
      for (int mb = 0; mb < 4; ++mb) {
        ah[mb] = *(const short8*)&lds[0 * 1024 + kgc * 128 + arow + mb * 16];
        al[mb] = *(const short8*)&lds[1 * 1024 + kgc * 128 + arow + mb * 16];
      }
      #pragma unroll
      for (int nb = 0; nb < 4; ++nb) {
        bh[nb] = *(const short8*)&lds[2 * 1024 + kgc * 128 + brow + nb * 16];
        bl[nb] = *(const short8*)&lds[3 * 1024 + kgc * 128 + brow + nb * 16];
      }
      #pragma unroll
      for (int mb = 0; mb < 4; ++mb)
        #pragma unroll
        for (int nb = 0; nb < 4; ++nb) {
          acc[mb][nb] = __builtin_amdgcn_mfma_f32_16x16x32_bf16(ah[mb], bh[nb], acc[mb][nb], 0, 0, 0);
          acc[mb][nb] = __builtin_amdgcn_mfma_f32_16x16x32_bf16(al[mb], bh[nb], acc[mb][nb], 0, 0, 0);
          acc[mb][nb] = __builtin_amdgcn_mfma_f32_16x16x32_bf16(ah[mb], bl[nb], acc[mb][nb], 0, 0, 0);
        }
    }
    __syncthreads();
    if (++sub == SUBS) { sub = 0; ++r; }
  }

  // epilogue: gates -> c/h update; nb index == gate (0=i 1=f 2=o 3=g)
  const int colq = nt * 128 + wave_n;
  const int hid  = ((colq >> 6) << 4) + (lane & 15);
  const int chout = (LAYER == 1) ? hid : 128 + hid;
  const float bi = bp[colq +      (lane & 15)];
  const float bf_ = bp[colq + 16 + (lane & 15)];
  const float bo = bp[colq + 32 + (lane & 15)];
  const float bg = bp[colq + 48 + (lane & 15)];
  #pragma unroll
  for (int mb = 0; mb < 4; ++mb) {
    #pragma unroll
    for (int rr = 0; rr < 4; ++rr) {
      const int m = mt * 128 + wave_m + mb * 16 + ((lane >> 4) << 2) + rr;
      if (m < MTOT) {
        const float gi = sigmoidf_(acc[mb][0][rr] + bi);
        const float gf = sigmoidf_(acc[mb][1][rr] + bf_);
        const float go = sigmoidf_(acc[mb][2][rr] + bo);
        const float gg = tanhf_   (acc[mb][3][rr] + bg);
        const size_t cidx = (size_t)m * NHID + hid;
        const float cn = gf * c[cidx] + gi * gg;
        c[cidx] = cn;
        const float h = go * tanhf_(cn);
        u32 hh, hl2; split2(h, hh, hl2);
        Shw[(size_t)m * 256 + chout] = (u16)hh;
        Slw[(size_t)m * 256 + chout] = (u16)hl2;
      }
    }
  }
}

// z-chunk 0..3 -> LAYER2(t), 4..7 -> LAYER1(t+1). XCD swizzle when 904 blocks.
__global__ __launch_bounds__(256, 2)
void steps_kernel(const float* __restrict__ x, int t1,
                  const u16* __restrict__ Shr, const u16* __restrict__ Slr,
                  u16* __restrict__ Shw, u16* __restrict__ Slw,
                  const u16* __restrict__ Wi1, const u16* __restrict__ Wi2,
                  const float* __restrict__ bp,
                  float* __restrict__ c1, float* __restrict__ c2,
                  const u16* __restrict__ zp, int do_l2) {
  __shared__ uint4 lds[4096];
  int bid = ((int)blockIdx.z * 4 + (int)blockIdx.y) * MT_TILES + (int)blockIdx.x;
  int nid = bid;
  if (gridDim.z == 2) nid = (bid & 7) * MT_TILES + (bid >> 3);  // 904 = 8*113 exact
  const int z  = nid / (MT_TILES * 4);
  const int rem = nid - z * (MT_TILES * 4);
  const int nt = rem / MT_TILES;
  const int mt = rem - nt * MT_TILES;
  if (z == 0 && do_l2)
    step_body<2>(lds, mt, nt, nullptr, 0, Shr, Slr, Shw, Slw, Wi2, bp + 512, c2, zp);
  else
    step_body<1>(lds, mt, nt, x, t1, Shr, Slr, Shw, Slw, Wi1, bp, c1, zp);
}

// ---------------- final dense ----------------
__global__ void dense_partial(const u16* __restrict__ Shi0, const u16* __restrict__ Slo0,
                              const float* __restrict__ Wd, float* __restrict__ part) {
  const int b = blockIdx.x, ks = blockIdx.y, n = threadIdx.x;
  float s = 0.f;
  for (int k = 0; k < 3600; ++k) {
    const int hidl = k / 225, pix = k - hidl * 225;
    const size_t si = ((size_t)(b * 225 + pix)) * 256 + 128 + ks * 16 + hidl;
    const float xv = bf2f(Shi0[si]) + bf2f(Slo0[si]);
    s = fmaf(xv, Wd[(size_t)(ks * 3600 + k) * 128 + n], s);
  }
  part[(b * 8 + ks) * 128 + n] = s;
}
__global__ void dense_reduce(const float* __restrict__ part, const float* __restrict__ bd,
                             float* __restrict__ out) {
  const int b = blockIdx.x, n = threadIdx.x;
  float s = bd[n];
  #pragma unroll
  for (int ks = 0; ks < 8; ++ks) s += part[(b * 8 + ks) * 128 + n];
  out[b * 128 + n] = s;
}

extern "C" void kernel_launch(void* const* d_in, const int* in_sizes, int n_in,
                              void* d_out, int out_size, void* d_ws, size_t ws_size,
                              hipStream_t stream) {
  const float* x  = (const float*)d_in[0];
  const float* W0 = (const float*)d_in[1];
  const float* b0 = (const float*)d_in[2];
  const float* W1 = (const float*)d_in[3];
  const float* b1 = (const float*)d_in[4];
  const float* Wd = (const float*)d_in[5];
  const float* bd = (const float*)d_in[6];

  const size_t PLANE = (size_t)MTOT * 256 * 2;      // 7,372,800 B (bf16 plane)
  const size_t CSZ   = (size_t)MTOT * NHID * 4;     // 7,372,800 B (f32 cell)
  char* base = (char*)d_ws;
  u16* zp = (u16*)base;                              // 4096 B zero page
  u16* Shi[2] = { (u16*)(base + 4096),             (u16*)(base + 4096 + PLANE) };
  u16* Slo[2] = { (u16*)(base + 4096 + 2 * PLANE), (u16*)(base + 4096 + 3 * PLANE) };
  float* c1 = (float*)(base + 4096 + 4 * PLANE);
  float* c2 = (float*)(base + 4096 + 4 * PLANE + CSZ);
  u16* Wi1 = (u16*)(base + 4096 + 4 * PLANE + 2 * CSZ);
  u16* Wi2 = Wi1 + L1IMG;
  float* bp = (float*)(Wi2 + L2IMG);
  float* part = bp + 1024;
  const size_t need = 4096 + 4 * PLANE + 2 * CSZ + (size_t)(L1IMG + L2IMG) * 2 +
                      1024 * 4 + 64 * 8 * 128 * 4;
  if (ws_size < need) return;

  hipMemsetAsync(d_ws, 0, 4096 + 4 * PLANE + 2 * CSZ, stream);
  prep_kernel<<<1024, 256, 0, stream>>>(W0, b0, W1, b1, Wi1, Wi2, bp);

  // launch k = -1..47: {L2(k) if k>=0} || {L1(k+1) if k<=46}
  for (int k = -1; k <= 47; ++k) {
    const int rd = k & 1, wr = (k + 1) & 1;
    const int dl2 = (k >= 0), dl1 = (k <= 46);
    dim3 grid(MT_TILES, 4, dl1 + dl2);
    steps_kernel<<<grid, 256, 0, stream>>>(x, k + 1, Shi[rd], Slo[rd], Shi[wr], Slo[wr],
                                           Wi1, Wi2, bp, c1, c2, zp, dl2);
  }
  // final h2(47) in Sbuf[0] ch[128:256)
  dense_partial<<<dim3(64, 8), 128, 0, stream>>>(Shi[0], Slo[0], Wd, part);
  dense_reduce<<<64, 128, 0, stream>>>(part, bd, (float*)d_out);
}

// Round 4
// 10754.081 us; speedup vs baseline: 1.4781x; 1.0790x over previous
//
#include <hip/hip_runtime.h>
#include <stdint.h>

// ConvLSTMDecoder: B=64 T=48 C_IN=64 HID=128 H=W=15 K=3 OUT=128
// R4: step kernel -> 2-phase double-buffered pipeline (BK=32, stage next
// overlaps MFMA of current, one barrier per phase); dense rewritten with
// LDS-staged feat + coalesced Wd (f32-exact).

typedef unsigned int u32;
typedef unsigned short u16;
typedef __attribute__((ext_vector_type(8))) short short8;   // 8 bf16
typedef __attribute__((ext_vector_type(4))) float f32x4;

#define NB   64
#define NT   48
#define NCX  64
#define NHID 128
#define NPIX 225
#define MTOT (NB*NPIX)      // 14400
#define MT_TILES 113
#define NK1  27             // K=1728 / 64
#define NK2  36             // K=2304 / 64
#define L1IMG (4*NK1*2*8192)   // bf16 elems of layer1 weight images
#define L2IMG (4*NK2*2*8192)

__device__ __forceinline__ u32 bf16_rne(u32 u) {
  return (u + 0x7fffu + ((u >> 16) & 1u)) >> 16;
}
__device__ __forceinline__ float bf2f(u16 h) { return __uint_as_float(((u32)h) << 16); }
__device__ __forceinline__ void split2(float f, u32& hi, u32& lo) {
  u32 u = __float_as_uint(f);
  hi = bf16_rne(u);
  lo = bf16_rne(__float_as_uint(f - __uint_as_float(hi << 16)));
}
__device__ __forceinline__ u32 packsplit(float f) { u32 h, l; split2(f, h, l); return (l << 16) | h; }
__device__ __forceinline__ void splitpair(u32 p0, u32 p1, u32& hw, u32& lw) {
  hw = __builtin_amdgcn_perm(p1, p0, 0x05040100u);
  lw = __builtin_amdgcn_perm(p1, p0, 0x07060302u);
}
__device__ __forceinline__ float sigmoidf_(float x) { return 1.f / (1.f + __expf(-x)); }
__device__ __forceinline__ float tanhf_(float x) {
  float e = __expf(-2.f * fabsf(x));
  return copysignf((1.f - e) / (1.f + e), x);
}
__device__ __forceinline__ void gl_lds16(const void* g, uint4* l) {
  __builtin_amdgcn_global_load_lds(
      (const __attribute__((address_space(1))) u32*)(g),
      (__attribute__((address_space(3))) u32*)(l), 16, 0, 0);
}

// ---------------- prep: weight LDS images (split + permuted) + bias ----------------
// image element e -> [img = ntkb*2+hl][kg(8)][qrow(128)][j(8)] bf16
// q = nt*128+qrow; hid=((q>>6)<<4)|(q&15); gate=(q>>4)&3; co=gate*128+hid
// k = kb*64+kg*8+j; r=k/CINL; ci=k%CINL;  W element = W[co][ci][r]
__global__ void prep_kernel(const float* __restrict__ W0, const float* __restrict__ b0,
                            const float* __restrict__ W1, const float* __restrict__ b1,
                            u16* __restrict__ Wi1, u16* __restrict__ Wi2,
                            float* __restrict__ bp) {
  const int total = L1IMG + L2IMG + 1024;
  for (int idx = blockIdx.x * blockDim.x + threadIdx.x; idx < total;
       idx += gridDim.x * blockDim.x) {
    if (idx < L1IMG + L2IMG) {
      const int layer2 = idx >= L1IMG;
      const int e = layer2 ? idx - L1IMG : idx;
      const int NK = layer2 ? NK2 : NK1;
      const int CINL = layer2 ? 256 : 192;
      const float* W = layer2 ? W1 : W0;
      const int img = e >> 13, o = e & 8191;
      const int hl = img & 1, ntkb = img >> 1;
      const int nt = ntkb / NK, kb = ntkb - nt * NK;
      const int kg = o >> 10, rem = o & 1023, qrow = rem >> 3, j = rem & 7;
      const int q = nt * 128 + qrow;
      const int hid = ((q >> 6) << 4) | (q & 15), gate = (q >> 4) & 3;
      const int co = gate * 128 + hid;
      const int k = kb * 64 + kg * 8 + j;
      const int r = k / CINL, ci = k - r * CINL;
      const float wv = W[(size_t)co * (CINL * 9) + ci * 9 + r];
      u32 hi, lo; split2(wv, hi, lo);
      (layer2 ? Wi2 : Wi1)[e] = (u16)(hl ? lo : hi);
    } else {
      const int e2 = idx - (L1IMG + L2IMG);
      const int l = e2 >> 9, q = e2 & 511;
      const int hid = ((q >> 6) << 4) | (q & 15), gate = (q >> 4) & 3;
      bp[e2] = (l == 0 ? b0 : b1)[gate * 128 + hid];
    }
  }
}

// ---------------- fused ConvLSTM step body (2-phase pipelined, BK=32) ----------------
// States: NHWC hi/lo bf16 planes S[b][pix][256]; ch[0:128)=h1, ch[128:256)=h2.
// LDS = 2 bufs x 32KB. Buf (uint4 units, 2048/buf):
//   A_hi [0,512) A_lo [512,1024) B_hi [1024,1536) B_lo [1536,2048)
//   each region [kg(4)][row(128)] uint4 (8 bf16). Conflict-free (R1: 0).
template <int LAYER>
__device__ __forceinline__ void step_body(
    uint4* lds4, int mt, int nt,
    const float* __restrict__ x, int t,
    const u16* __restrict__ Shr, const u16* __restrict__ Slr,
    u16* __restrict__ Shw, u16* __restrict__ Slw,
    const u16* __restrict__ Wimg, const float* __restrict__ bp,
    float* __restrict__ c, const u16* __restrict__ zp)
{
  constexpr int SUB32 = (LAYER == 1) ? 6 : 8;   // 32-ch sub-steps per tap
  constexpr int NK64  = (LAYER == 1) ? NK1 : NK2;

  const int tid = threadIdx.x;
  const int lane = tid & 63, w = tid >> 6;
  const int wave_m = (w >> 1) * 64, wave_n = (w & 1) * 64;

  // staging segments i=0,1: kg = w, row = i*64+lane
  int abase[2], xbase[2], phh[2], pww[2];
  bool mok[2];
  #pragma unroll
  for (int i = 0; i < 2; ++i) {
    const int row = i * 64 + lane;
    const int m = mt * 128 + row;
    mok[i] = m < MTOT;
    const int mm = mok[i] ? m : 0;
    const int b = mm / 225, p = mm - b * 225;
    phh[i] = p / 15; pww[i] = p - phh[i] * 15;
    abase[i] = mm * 512 + w * 16;                       // state plane byte offset
    xbase[i] = ((b * NT + t) * NCX) * NPIX + p;         // x f32 elem offset
  }

  f32x4 acc[4][4];
  #pragma unroll
  for (int i = 0; i < 4; ++i)
    #pragma unroll
    for (int j = 0; j < 4; ++j) acc[i][j] = (f32x4){0.f, 0.f, 0.f, 0.f};

  // ---- staging helpers ----
  auto stageB = [&](int ph, uint4* dst) {
    const size_t imgu16 = (size_t)((nt * NK64 + (ph >> 1)) * 2) * 16384;  // hi image bytes
    const int half = ph & 1;
    #pragma unroll
    for (int i = 0; i < 2; ++i) {
      const size_t su = imgu16 + (size_t)((half * 4 + w) * 128 + i * 64 + lane) * 16;
      gl_lds16((const char*)Wimg + su,         dst + 1024 + w * 128 + i * 64);
      gl_lds16((const char*)Wimg + su + 16384, dst + 1536 + w * 128 + i * 64);
    }
  };
  auto stageA_gl = [&](int sub, int dp, const bool* v, uint4* dst) {
    const int icb = (LAYER == 1) ? (sub - 2) * 64 : sub * 64;
    const int du = dp * 512 + icb;
    #pragma unroll
    for (int i = 0; i < 2; ++i) {
      const char* gh = v[i] ? (const char*)Shr + (abase[i] + du) : (const char*)zp;
      const char* gl = v[i] ? (const char*)Slr + (abase[i] + du) : (const char*)zp;
      gl_lds16(gh, dst +       w * 128 + i * 64);
      gl_lds16(gl, dst + 512 + w * 128 + i * 64);
    }
  };
  auto stageA_x = [&](int sub, int dp, const bool* v, uint4* dst) {
    #pragma unroll
    for (int i = 0; i < 2; ++i) {
      const float* src = x + xbase[i] + (sub * 32 + w * 8) * NPIX + dp;
      u32 hw_[4], lw_[4];
      #pragma unroll
      for (int jj = 0; jj < 4; ++jj) {
        const float f0 = v[i] ? src[(2 * jj) * NPIX] : 0.f;
        const float f1 = v[i] ? src[(2 * jj + 1) * NPIX] : 0.f;
        splitpair(packsplit(f0), packsplit(f1), hw_[jj], lw_[jj]);
      }
      dst[      w * 128 + i * 64 + lane] = make_uint4(hw_[0], hw_[1], hw_[2], hw_[3]);
      dst[512 + w * 128 + i * 64 + lane] = make_uint4(lw_[0], lw_[1], lw_[2], lw_[3]);
    }
  };
  auto domfma = [&](const uint4* src) {
    const int kgc  = lane >> 4;
    const int arow = wave_m + (lane & 15);
    const int brow = wave_n + (lane & 15);
    short8 ah[4], al[4], bh[4], bl[4];
    #pragma unroll
    for (int mb = 0; mb < 4; ++mb) {
      ah[mb] = *(const short8*)&src[       kgc * 128 + arow + mb * 16];
      al[mb] = *(const short8*)&src[ 512 + kgc * 128 + arow + mb * 16];
    }
    #pragma unroll
    for (int nb = 0; nb < 4; ++nb) {
      bh[nb] = *(const short8*)&src[1024 + kgc * 128 + brow + nb * 16];
      bl[nb] = *(const short8*)&src[1536 + kgc * 128 + brow + nb * 16];
    }
    #pragma unroll
    for (int mb = 0; mb < 4; ++mb)
      #pragma unroll
      for (int nb = 0; nb < 4; ++nb) {
        acc[mb][nb] = __builtin_amdgcn_mfma_f32_16x16x32_bf16(ah[mb], bh[nb], acc[mb][nb], 0, 0, 0);
        acc[mb][nb] = __builtin_amdgcn_mfma_f32_16x16x32_bf16(al[mb], bh[nb], acc[mb][nb], 0, 0, 0);
        acc[mb][nb] = __builtin_amdgcn_mfma_f32_16x16x32_bf16(ah[mb], bl[nb], acc[mb][nb], 0, 0, 0);
      }
  };

  // ---- prologue: stage phase 0 (tap (-1,-1), sub 0) into buf 0 ----
  {
    bool v[2];
    #pragma unroll
    for (int i = 0; i < 2; ++i) v[i] = mok[i] && (phh[i] >= 1) && (pww[i] >= 1);
    stageB(0, lds4);
    if (LAYER == 1) stageA_x(0, -16, v, lds4);
    else            stageA_gl(0, -16, v, lds4);
  }
  __syncthreads();

  // ---- main: 9 taps x SUB32 phases, stage(next) || mfma(cur) ----
  int cur = 0;
  int dr = -1, dc = -1;
  for (int r = 0; r < 9; ++r) {
    const int dp  = dr * 15 + dc;
    const int drn = (dc == 1) ? dr + 1 : dr;
    const int dcn = (dc == 1) ? -1 : dc + 1;
    const int dpn = drn * 15 + dcn;
    bool vc[2], vn[2];
    #pragma unroll
    for (int i = 0; i < 2; ++i) {
      vc[i] = mok[i] && ((unsigned)(phh[i] + dr)  < 15u) && ((unsigned)(pww[i] + dc)  < 15u);
      vn[i] = mok[i] && ((unsigned)(phh[i] + drn) < 15u) && ((unsigned)(pww[i] + dcn) < 15u);
    }
    #pragma unroll
    for (int s = 0; s < SUB32; ++s) {
      uint4* nbuf = lds4 + (cur ^ 1) * 2048;
      const int ph = r * SUB32 + s;
      if (s + 1 < SUB32) {
        stageB(ph + 1, nbuf);
        if (LAYER == 1 && (s + 1) < 2) stageA_x(s + 1, dp, vc, nbuf);
        else                           stageA_gl(s + 1, dp, vc, nbuf);
      } else if (r < 8) {
        stageB(ph + 1, nbuf);
        if (LAYER == 1) stageA_x(0, dpn, vn, nbuf);
        else            stageA_gl(0, dpn, vn, nbuf);
      }
      domfma(lds4 + cur * 2048);
      __syncthreads();
      cur ^= 1;
    }
    dr = drn; dc = dcn;
  }

  // ---- epilogue: gates -> c/h update; nb index == gate (0=i 1=f 2=o 3=g) ----
  const int colq = nt * 128 + wave_n;
  const int hid  = ((colq >> 6) << 4) + (lane & 15);
  const int chout = (LAYER == 1) ? hid : 128 + hid;
  const float bi  = bp[colq +      (lane & 15)];
  const float bf_ = bp[colq + 16 + (lane & 15)];
  const float bo  = bp[colq + 32 + (lane & 15)];
  const float bg  = bp[colq + 48 + (lane & 15)];
  #pragma unroll
  for (int mb = 0; mb < 4; ++mb) {
    #pragma unroll
    for (int rr = 0; rr < 4; ++rr) {
      const int m = mt * 128 + wave_m + mb * 16 + ((lane >> 4) << 2) + rr;
      if (m < MTOT) {
        const float gi = sigmoidf_(acc[mb][0][rr] + bi);
        const float gf = sigmoidf_(acc[mb][1][rr] + bf_);
        const float go = sigmoidf_(acc[mb][2][rr] + bo);
        const float gg = tanhf_   (acc[mb][3][rr] + bg);
        const size_t cidx = (size_t)m * NHID + hid;
        const float cn = gf * c[cidx] + gi * gg;
        c[cidx] = cn;
        const float h = go * tanhf_(cn);
        u32 hh, hl2; split2(h, hh, hl2);
        Shw[(size_t)m * 256 + chout] = (u16)hh;
        Slw[(size_t)m * 256 + chout] = (u16)hl2;
      }
    }
  }
}

// z-chunk 0..3 -> LAYER2(t), 4..7 -> LAYER1(t+1). XCD swizzle when 904 blocks.
__global__ __launch_bounds__(256, 2)
void steps_kernel(const float* __restrict__ x, int t1,
                  const u16* __restrict__ Shr, const u16* __restrict__ Slr,
                  u16* __restrict__ Shw, u16* __restrict__ Slw,
                  const u16* __restrict__ Wi1, const u16* __restrict__ Wi2,
                  const float* __restrict__ bp,
                  float* __restrict__ c1, float* __restrict__ c2,
                  const u16* __restrict__ zp, int do_l2) {
  __shared__ uint4 lds4[4096];
  int bid = ((int)blockIdx.z * 4 + (int)blockIdx.y) * MT_TILES + (int)blockIdx.x;
  int nid = bid;
  if (gridDim.z == 2) nid = (bid & 7) * MT_TILES + (bid >> 3);  // 904 = 8*113 exact
  const int z   = nid / (MT_TILES * 4);
  const int rem = nid - z * (MT_TILES * 4);
  const int nt  = rem / MT_TILES;
  const int mt  = rem - nt * MT_TILES;
  if (z == 0 && do_l2)
    step_body<2>(lds4, mt, nt, nullptr, 0, Shr, Slr, Shw, Slw, Wi2, bp + 512, c2, zp);
  else
    step_body<1>(lds4, mt, nt, x, t1, Shr, Slr, Shw, Slw, Wi1, bp, c1, zp);
}

// ---------------- final dense: feat[64][28800] @ Wd[28800][128] + bd ----------------
// block (b, ks): k-rows [ks*1800, +1800) = hid [ks*8, ks*8+8), all 225 pix.
__global__ __launch_bounds__(256)
void dense_kernel(const u16* __restrict__ Shi0, const u16* __restrict__ Slo0,
                  const float* __restrict__ Wd, float* __restrict__ part) {
  __shared__ float sfeat[1800];
  __shared__ float red[128];
  const int b = blockIdx.x, ks = blockIdx.y, tid = threadIdx.x;
  for (int idx = tid; idx < 1800; idx += 256) {
    const int hid_l = idx & 7, pix = idx >> 3;
    const size_t si = ((size_t)(b * 225 + pix)) * 256 + 128 + ks * 8 + hid_l;
    sfeat[hid_l * 225 + pix] = bf2f(Shi0[si]) + bf2f(Slo0[si]);
  }
  __syncthreads();
  const int kk2 = tid >> 7, n = tid & 127;
  const float* wdp = Wd + (size_t)ks * 1800 * 128 + n;
  float s = 0.f;
  #pragma unroll 4
  for (int i = kk2; i < 1800; i += 2)
    s = fmaf(sfeat[i], wdp[(size_t)i * 128], s);
  if (kk2) red[n] = s;
  __syncthreads();
  if (!kk2) part[((size_t)b * 16 + ks) * 128 + n] = s + red[n];
}
__global__ void dense_reduce(const float* __restrict__ part, const float* __restrict__ bd,
                             float* __restrict__ out) {
  const int b = blockIdx.x, n = threadIdx.x;
  float s = bd[n];
  #pragma unroll
  for (int ks = 0; ks < 16; ++ks) s += part[((size_t)b * 16 + ks) * 128 + n];
  out[b * 128 + n] = s;
}

extern "C" void kernel_launch(void* const* d_in, const int* in_sizes, int n_in,
                              void* d_out, int out_size, void* d_ws, size_t ws_size,
                              hipStream_t stream) {
  const float* x  = (const float*)d_in[0];
  const float* W0 = (const float*)d_in[1];
  const float* b0 = (const float*)d_in[2];
  const float* W1 = (const float*)d_in[3];
  const float* b1 = (const float*)d_in[4];
  const float* Wd = (const float*)d_in[5];
  const float* bd = (const float*)d_in[6];

  const size_t PLANE = (size_t)MTOT * 256 * 2;      // 7,372,800 B (bf16 plane)
  const size_t CSZ   = (size_t)MTOT * NHID * 4;     // 7,372,800 B (f32 cell)
  char* base = (char*)d_ws;
  u16* zp = (u16*)base;                              // 4096 B zero page
  u16* Shi[2] = { (u16*)(base + 4096),             (u16*)(base + 4096 + PLANE) };
  u16* Slo[2] = { (u16*)(base + 4096 + 2 * PLANE), (u16*)(base + 4096 + 3 * PLANE) };
  float* c1 = (float*)(base + 4096 + 4 * PLANE);
  float* c2 = (float*)(base + 4096 + 4 * PLANE + CSZ);
  u16* Wi1 = (u16*)(base + 4096 + 4 * PLANE + 2 * CSZ);
  u16* Wi2 = Wi1 + L1IMG;
  float* bp = (float*)(Wi2 + L2IMG);
  float* part = bp + 1024;                           // 64*16*128 f32
  const size_t need = 4096 + 4 * PLANE + 2 * CSZ + (size_t)(L1IMG + L2IMG) * 2 +
                      1024 * 4 + (size_t)64 * 16 * 128 * 4;
  if (ws_size < need) return;

  hipMemsetAsync(d_ws, 0, 4096 + 4 * PLANE + 2 * CSZ, stream);
  prep_kernel<<<1024, 256, 0, stream>>>(W0, b0, W1, b1, Wi1, Wi2, bp);

  // launch k = -1..47: {L2(k) if k>=0} || {L1(k+1) if k<=46}
  for (int k = -1; k <= 47; ++k) {
    const int rd = k & 1, wr = (k + 1) & 1;
    const int dl2 = (k >= 0), dl1 = (k <= 46);
    dim3 grid(MT_TILES, 4, dl1 + dl2);
    steps_kernel<<<grid, 256, 0, stream>>>(x, k + 1, Shi[rd], Slo[rd], Shi[wr], Slo[wr],
                                           Wi1, Wi2, bp, c1, c2, zp, dl2);
  }
  // final h2(47) in Sbuf[0] ch[128:256)
  dense_kernel<<<dim3(64, 16), 256, 0, stream>>>(Shi[0], Slo[0], Wd, part);
  dense_reduce<<<64, 128, 0, stream>>>(part, bd, (float*)d_out);
}

// Round 5
// 9225.981 us; speedup vs baseline: 1.7230x; 1.1656x over previous
//
#include <hip/hip_runtime.h>
#include <stdint.h>

// ConvLSTMDecoder: B=64 T=48 C_IN=64 HID=128 H=W=15 K=3 OUT=128
// R5: zero-ring padded planes [b][17][17][ch] + per-cg LDS halo tile;
// taps inner (9x reuse from LDS); K-order (cg,tap,ch8); B-images dbuf per
// tap-phase; x converted once per cg during A-stage. Split-bf16 MFMA (3x).

typedef unsigned int u32;
typedef unsigned short u16;
typedef __attribute__((ext_vector_type(8))) short short8;   // 8 bf16
typedef __attribute__((ext_vector_type(4))) float f32x4;

#define NB    64
#define NT    48
#define NCX   64
#define NHID  128
#define NPIX  225
#define MTOT  (NB*NPIX)     // 14400
#define MT_TILES 113
#define RROWS 18544         // 64*289 = 18496 valid + tail pad (stage window safe)
#define AROWS 224           // LDS halo rows per cg (max span ~218)
#define L1BLK 216           // 4 nt * 6 cg * 9 tap
#define L2BLK 288           // 4 nt * 8 cg * 9 tap

__device__ __forceinline__ u32 bf16_rne(u32 u) {
  return (u + 0x7fffu + ((u >> 16) & 1u)) >> 16;
}
__device__ __forceinline__ float bf2f(u16 h) { return __uint_as_float(((u32)h) << 16); }
__device__ __forceinline__ void split2(float f, u32& hi, u32& lo) {
  u32 u = __float_as_uint(f);
  hi = bf16_rne(u);
  lo = bf16_rne(__float_as_uint(f - __uint_as_float(hi << 16)));
}
__device__ __forceinline__ void splitpair(u32 p0, u32 p1, u32& hw, u32& lw) {
  u32 s0, s1; u32 h0, l0, h1, l1;
  split2(__uint_as_float(p0), h0, l0);   // here p0,p1 are float bits
  split2(__uint_as_float(p1), h1, l1);
  hw = (h1 << 16) | h0; lw = (l1 << 16) | l0;
  (void)s0; (void)s1;
}
__device__ __forceinline__ float sigmoidf_(float x) { return 1.f / (1.f + __expf(-x)); }
__device__ __forceinline__ float tanhf_(float x) {
  float e = __expf(-2.f * fabsf(x));
  return copysignf((1.f - e) / (1.f + e), x);
}
__device__ __forceinline__ void gl_lds16(const void* g, void* l) {
  __builtin_amdgcn_global_load_lds(
      (const __attribute__((address_space(1))) u32*)(g),
      (__attribute__((address_space(3))) u32*)(l), 16, 0, 0);
}

// ---------------- prep: weight images, K-order (cg, tap, ch8) ----------------
// block idx: L1: (nt*6+cg)*9+tap ; L2: L1BLK + (nt*8+cg)*9+tap. 16KB each:
// [pl2][kg4][qrow128][j8] bf16.  q=nt*128+qrow -> co=gate*128+hid (permuted);
// ci = cg*32+kg*8+j (concat channel); element W[co][ci][tap].
__global__ void prep_kernel(const float* __restrict__ W0, const float* __restrict__ b0,
                            const float* __restrict__ W1, const float* __restrict__ b1,
                            u16* __restrict__ Wi, float* __restrict__ bp) {
  const int total = (L1BLK + L2BLK) * 8192 + 1024;
  for (int idx = blockIdx.x * blockDim.x + threadIdx.x; idx < total;
       idx += gridDim.x * blockDim.x) {
    if (idx < (L1BLK + L2BLK) * 8192) {
      const int blk = idx >> 13, o = idx & 8191;
      int nt, cg, tap, CINL;
      const float* W;
      if (blk < L1BLK) { nt = blk / 54; cg = (blk % 54) / 9; tap = blk % 9; CINL = 192; W = W0; }
      else { const int b2 = blk - L1BLK; nt = b2 / 72; cg = (b2 % 72) / 9; tap = b2 % 9; CINL = 256; W = W1; }
      const int pl = o >> 12, kg = (o >> 10) & 3, qrow = (o >> 3) & 127, j = o & 7;
      const int q = nt * 128 + qrow;
      const int hid = ((q >> 6) << 4) | (q & 15), gate = (q >> 4) & 3;
      const int co = gate * 128 + hid;
      const int ci = cg * 32 + kg * 8 + j;
      const float wv = W[(size_t)co * (CINL * 9) + ci * 9 + tap];
      u32 hi, lo; split2(wv, hi, lo);
      Wi[idx] = (u16)(pl ? lo : hi);
    } else {
      const int e2 = idx - (L1BLK + L2BLK) * 8192;
      const int l = e2 >> 9, q = e2 & 511;
      const int hid = ((q >> 6) << 4) | (q & 15), gate = (q >> 4) & 3;
      bp[e2] = (l == 0 ? b0 : b1)[gate * 128 + hid];
    }
  }
}

// ---------------- fused ConvLSTM step body ----------------
// LDS: A halo [pl2][kg4][row224] uint4 = 28672 B at ldsA;
//      B dbuf 2 x [pl2][kg4][qrow128] uint4 = 2 x 16384 B at ldsB.
template <int LAYER>
__device__ __forceinline__ void step_body(
    uint4* ldsA, uint4* ldsB, int mt, int nt,
    const float* __restrict__ x, int t,
    const u16* __restrict__ P1h, const u16* __restrict__ P1l,
    const u16* __restrict__ P2h, const u16* __restrict__ P2l,
    u16* __restrict__ Wh, u16* __restrict__ Wl,
    const u16* __restrict__ Wimg, const float* __restrict__ bp,
    float* __restrict__ c)
{
  constexpr int CG = (LAYER == 1) ? 6 : 8;
  const int tid = threadIdx.x, lane = tid & 63, w = tid >> 6;
  const int wave_m = (w >> 1) * 64, wave_n = (w & 1) * 64;
  const int kgc = lane >> 4, l15 = lane & 15;

  const int m0 = mt * 128;
  const int b0v = m0 / 225, p0v = m0 - b0v * 225;
  const int r0 = b0v * 289 + (p0v / 15) * 17 + (p0v % 15);   // r(m0) - 18

  // per-lane fragment bases
  int aoff[4];
  #pragma unroll
  for (int mb = 0; mb < 4; ++mb) {
    int m = m0 + wave_m + mb * 16 + l15; if (m > 14399) m = 14399;
    const int b = m / 225, p = m - b * 225;
    const int r = b * 289 + (p / 15) * 17 + (p % 15) + 18;
    aoff[mb] = (kgc * AROWS + (r - r0 - 18)) * 16;
  }
  int boff[4];
  #pragma unroll
  for (int nb = 0; nb < 4; ++nb) boff[nb] = (kgc * 128 + wave_n + l15 + nb * 16) * 16;

  f32x4 acc[4][4];
  #pragma unroll
  for (int i = 0; i < 4; ++i)
    #pragma unroll
    for (int j = 0; j < 4; ++j) acc[i][j] = (f32x4){0.f, 0.f, 0.f, 0.f};

  // ---- staging helpers ----
  auto stageA_h = [&](const u16* __restrict__ Ph, const u16* __restrict__ Pl, int choff) {
    #pragma unroll
    for (int i = 0; i < 7; ++i) {
      const int chunk = w * 7 + i;
      const int e = chunk * 64 + lane;
      const int pk = e / AROWS, row = e - pk * AROWS;
      const int kg = pk & 3;
      const u16* P = (pk >= 4) ? Pl : Ph;
      const char* src = (const char*)P + ((size_t)(r0 + row) * 128 + choff + kg * 8) * 2;
      gl_lds16(src, (char*)ldsA + chunk * 1024);
    }
  };
  auto stageA_x = [&](int cg) {
    for (int tau = tid; tau < 4 * AROWS; tau += 256) {
      const int kg = tau / AROWS, row = tau - kg * AROWS;
      const int rg = r0 + row;
      const int rb = rg / 289, rr = rg - rb * 289;
      const int rh = rr / 17 - 1, rw = rr - (rr / 17) * 17 - 1;
      const bool v = ((unsigned)rh < 15u) && ((unsigned)rw < 15u) && (rb < 64);
      const int p = rh * 15 + rw;
      const float* src = x + (((size_t)rb * NT + t) * NCX + cg * 32 + kg * 8) * NPIX + p;
      u32 hw_[4], lw_[4];
      #pragma unroll
      for (int jj = 0; jj < 4; ++jj) {
        const float f0 = v ? src[(2 * jj) * NPIX] : 0.f;
        const float f1 = v ? src[(2 * jj + 1) * NPIX] : 0.f;
        u32 h0, l0, h1, l1;
        split2(f0, h0, l0); split2(f1, h1, l1);
        hw_[jj] = (h1 << 16) | h0; lw_[jj] = (l1 << 16) | l0;
      }
      ldsA[kg * AROWS + row]       = make_uint4(hw_[0], hw_[1], hw_[2], hw_[3]);
      ldsA[(4 + kg) * AROWS + row] = make_uint4(lw_[0], lw_[1], lw_[2], lw_[3]);
    }
  };
  auto stageB = [&](int cg, int tap, int bufsel) {
    const char* src = (const char*)Wimg + ((size_t)((nt * CG + cg) * 9 + tap) << 14);
    char* dstb = (char*)(ldsB + bufsel * 1024);
    #pragma unroll
    for (int j = 0; j < 4; ++j) {
      const int chunk = w * 4 + j;
      gl_lds16(src + chunk * 1024 + lane * 16, dstb + chunk * 1024);
    }
  };

  // ---- main: CG groups x 9 taps; A staged once per cg, B dbuf per tap ----
  int bufsel = 0;
  for (int cg = 0; cg < CG; ++cg) {
    if (LAYER == 1 && cg < 2) stageA_x(cg);
    else if (LAYER == 1)      stageA_h(P1h, P1l, (cg - 2) * 32);
    else if (cg < 4)          stageA_h(P1h, P1l, cg * 32);
    else                      stageA_h(P2h, P2l, (cg - 4) * 32);
    if (cg == 0) stageB(0, 0, bufsel);
    __syncthreads();

    #pragma unroll
    for (int tap = 0; tap < 9; ++tap) {
      if (tap < 8)            stageB(cg, tap + 1, bufsel ^ 1);
      else if (cg + 1 < CG)   stageB(cg + 1, 0, bufsel ^ 1);
      // MFMA on current buffers; tap shift is a compile-time immediate
      {
        const int DPO = ((tap / 3) * 17 + (tap % 3)) * 16;   // (18+dp)*16
        const char* A  = (const char*)ldsA;
        const char* Bb = (const char*)(ldsB + bufsel * 1024);
        short8 ah[4], al[4], bh[4], bl[4];
        #pragma unroll
        for (int mb = 0; mb < 4; ++mb) {
          ah[mb] = *(const short8*)(A + aoff[mb] + DPO);
          al[mb] = *(const short8*)(A + aoff[mb] + DPO + 14336);
        }
        #pragma unroll
        for (int nb = 0; nb < 4; ++nb) {
          bh[nb] = *(const short8*)(Bb + boff[nb]);
          bl[nb] = *(const short8*)(Bb + boff[nb] + 8192);
        }
        __builtin_amdgcn_s_setprio(1);
        #pragma unroll
        for (int mb = 0; mb < 4; ++mb)
          #pragma unroll
          for (int nb = 0; nb < 4; ++nb) {
            acc[mb][nb] = __builtin_amdgcn_mfma_f32_16x16x32_bf16(ah[mb], bh[nb], acc[mb][nb], 0, 0, 0);
            acc[mb][nb] = __builtin_amdgcn_mfma_f32_16x16x32_bf16(al[mb], bh[nb], acc[mb][nb], 0, 0, 0);
            acc[mb][nb] = __builtin_amdgcn_mfma_f32_16x16x32_bf16(ah[mb], bl[nb], acc[mb][nb], 0, 0, 0);
          }
        __builtin_amdgcn_s_setprio(0);
      }
      __syncthreads();
      bufsel ^= 1;
    }
  }

  // ---- epilogue: gates -> c/h update; nb index == gate (0=i 1=f 2=o 3=g) ----
  const int colq = nt * 128 + wave_n;
  const int hid  = ((colq >> 6) << 4) + l15;
  const float bi  = bp[colq +      l15];
  const float bf_ = bp[colq + 16 + l15];
  const float bo  = bp[colq + 32 + l15];
  const float bg  = bp[colq + 48 + l15];
  #pragma unroll
  for (int mb = 0; mb < 4; ++mb) {
    #pragma unroll
    for (int rr = 0; rr < 4; ++rr) {
      const int m = m0 + wave_m + mb * 16 + ((lane >> 4) << 2) + rr;
      if (m < MTOT) {
        const float gi = sigmoidf_(acc[mb][0][rr] + bi);
        const float gf = sigmoidf_(acc[mb][1][rr] + bf_);
        const float go = sigmoidf_(acc[mb][2][rr] + bo);
        const float gg = tanhf_   (acc[mb][3][rr] + bg);
        const size_t cidx = (size_t)m * NHID + hid;
        const float cn = gf * c[cidx] + gi * gg;
        c[cidx] = cn;
        const float h = go * tanhf_(cn);
        u32 hh, hl2; split2(h, hh, hl2);
        const int b = m / 225, p = m - b * 225;
        const size_t r = (size_t)b * 289 + (p / 15) * 17 + (p % 15) + 18;
        Wh[r * 128 + hid] = (u16)hh;
        Wl[r * 128 + hid] = (u16)hl2;
      }
    }
  }
}

// z=0 -> L2(t) (if do_l2 else L1), z=1 -> L1(t+1). XCD swizzle at 904 blocks.
__global__ __launch_bounds__(256, 2)
void steps_kernel(const float* __restrict__ x, int t1,
                  const u16* __restrict__ h1hr, const u16* __restrict__ h1lr,
                  const u16* __restrict__ h2hr, const u16* __restrict__ h2lr,
                  u16* __restrict__ h1hw, u16* __restrict__ h1lw,
                  u16* __restrict__ h2hw, u16* __restrict__ h2lw,
                  const u16* __restrict__ Wi, const float* __restrict__ bp,
                  float* __restrict__ c1, float* __restrict__ c2, int do_l2) {
  __shared__ uint4 ldsA[1792];   // 28672 B
  __shared__ uint4 ldsB[2048];   // 32768 B
  int bid = ((int)blockIdx.z * 4 + (int)blockIdx.y) * MT_TILES + (int)blockIdx.x;
  int nid = bid;
  if (gridDim.z == 2) nid = (bid & 7) * MT_TILES + (bid >> 3);  // 904 = 8*113
  const int z   = nid / (MT_TILES * 4);
  const int rem = nid - z * (MT_TILES * 4);
  const int nt  = rem / MT_TILES;
  const int mt  = rem - nt * MT_TILES;
  if (z == 0 && do_l2)
    step_body<2>(ldsA, ldsB, mt, nt, nullptr, 0, h1hr, h1lr, h2hr, h2lr,
                 h2hw, h2lw, Wi + (size_t)L1BLK * 8192, bp + 512, c2);
  else
    step_body<1>(ldsA, ldsB, mt, nt, x, t1, h1hr, h1lr, nullptr, nullptr,
                 h1hw, h1lw, Wi, bp, c1);
}

// ---------------- final dense: feat[64][28800] @ Wd[28800][128] + bd ----------------
__global__ __launch_bounds__(256)
void dense_kernel(const u16* __restrict__ H2h, const u16* __restrict__ H2l,
                  const float* __restrict__ Wd, float* __restrict__ part) {
  __shared__ float sfeat[1800];
  __shared__ float red[128];
  const int b = blockIdx.x, ks = blockIdx.y, tid = threadIdx.x;
  for (int idx = tid; idx < 1800; idx += 256) {
    const int hid_l = idx & 7, pix = idx >> 3;
    const size_t r = (size_t)b * 289 + (pix / 15) * 17 + (pix % 15) + 18;
    const size_t si = r * 128 + ks * 8 + hid_l;
    sfeat[hid_l * 225 + pix] = bf2f(H2h[si]) + bf2f(H2l[si]);
  }
  __syncthreads();
  const int kk2 = tid >> 7, n = tid & 127;
  const float* wdp = Wd + (size_t)ks * 1800 * 128 + n;
  float s = 0.f;
  #pragma unroll 4
  for (int i = kk2; i < 1800; i += 2)
    s = fmaf(sfeat[i], wdp[(size_t)i * 128], s);
  if (kk2) red[n] = s;
  __syncthreads();
  if (!kk2) part[((size_t)b * 16 + ks) * 128 + n] = s + red[n];
}
__global__ void dense_reduce(const float* __restrict__ part, const float* __restrict__ bd,
                             float* __restrict__ out) {
  const int b = blockIdx.x, n = threadIdx.x;
  float s = bd[n];
  #pragma unroll
  for (int ks = 0; ks < 16; ++ks) s += part[((size_t)b * 16 + ks) * 128 + n];
  out[b * 128 + n] = s;
}

extern "C" void kernel_launch(void* const* d_in, const int* in_sizes, int n_in,
                              void* d_out, int out_size, void* d_ws, size_t ws_size,
                              hipStream_t stream) {
  const float* x  = (const float*)d_in[0];
  const float* W0 = (const float*)d_in[1];
  const float* b0 = (const float*)d_in[2];
  const float* W1 = (const float*)d_in[3];
  const float* b1 = (const float*)d_in[4];
  const float* Wd = (const float*)d_in[5];
  const float* bd = (const float*)d_in[6];

  const size_t HPB = (size_t)RROWS * 128 * 2;   // 4,747,264 B per plane
  const size_t CSZ = (size_t)MTOT * NHID * 4;   // 7,372,800 B
  char* base = (char*)d_ws;
  u16* h1h[2] = { (u16*)(base),            (u16*)(base + HPB) };
  u16* h1l[2] = { (u16*)(base + 2 * HPB),  (u16*)(base + 3 * HPB) };
  u16* h2h[2] = { (u16*)(base + 4 * HPB),  (u16*)(base + 5 * HPB) };
  u16* h2l[2] = { (u16*)(base + 6 * HPB),  (u16*)(base + 7 * HPB) };
  float* c1 = (float*)(base + 8 * HPB);
  float* c2 = (float*)(base + 8 * HPB + CSZ);
  u16* Wi   = (u16*)(base + 8 * HPB + 2 * CSZ);
  const size_t WIB = (size_t)(L1BLK + L2BLK) * 16384;
  float* bp   = (float*)((char*)Wi + WIB);
  float* part = bp + 1024;
  const size_t need = 8 * HPB + 2 * CSZ + WIB + 1024 * 4 + (size_t)64 * 16 * 128 * 4;
  if (ws_size < need) return;

  // zero planes + cells (zero ring of padded planes + initial states)
  hipMemsetAsync(d_ws, 0, 8 * HPB + 2 * CSZ, stream);
  prep_kernel<<<2048, 256, 0, stream>>>(W0, b0, W1, b1, Wi, bp);

  // launch k = -1..47: {L2(k) if k>=0} || {L1(k+1) if k<=46}
  for (int k = -1; k <= 47; ++k) {
    const int rd = k & 1, wr = (k + 1) & 1;
    const int dl2 = (k >= 0), dl1 = (k <= 46);
    dim3 grid(MT_TILES, 4, dl1 + dl2);
    steps_kernel<<<grid, 256, 0, stream>>>(x, k + 1,
        h1h[rd], h1l[rd], h2h[rd], h2l[rd],
        h1h[wr], h1l[wr], h2h[wr], h2l[wr],
        Wi, bp, c1, c2, dl2);
  }
  // final h2(47) in buf 0
  dense_kernel<<<dim3(64, 16), 256, 0, stream>>>(h2h[0], h2l[0], Wd, part);
  dense_reduce<<<64, 128, 0, stream>>>(part, bd, (float*)d_out);
}

// Round 6
// 8446.559 us; speedup vs baseline: 1.8820x; 1.0923x over previous
//
#include <hip/hip_runtime.h>
#include <stdint.h>

// ConvLSTMDecoder: B=64 T=48 C_IN=64 HID=128 H=W=15 K=3 OUT=128
// R6: B (weights) -> registers (L2-resident images, dbuf one tap ahead);
// per-tap barriers eliminated (1 barrier/cg). A halo double-buffered in LDS
// (2x28KB), staged via gl_lds overlapping the 9-tap MFMA stream.

typedef unsigned int u32;
typedef unsigned short u16;
typedef __attribute__((ext_vector_type(8))) short short8;   // 8 bf16
typedef __attribute__((ext_vector_type(4))) float f32x4;

#define NB    64
#define NT    48
#define NCX   64
#define NHID  128
#define NPIX  225
#define MTOT  (NB*NPIX)     // 14400
#define MT_TILES 113
#define RROWS 18624         // 64*289 = 18496 valid + stage-window pad
#define AROWS 224           // LDS halo rows per cg (max span ~215+36)
#define L1BLK 216           // 4 nt * 6 cg * 9 tap
#define L2BLK 288           // 4 nt * 8 cg * 9 tap

__device__ __forceinline__ u32 bf16_rne(u32 u) {
  return (u + 0x7fffu + ((u >> 16) & 1u)) >> 16;
}
__device__ __forceinline__ float bf2f(u16 h) { return __uint_as_float(((u32)h) << 16); }
__device__ __forceinline__ void split2(float f, u32& hi, u32& lo) {
  u32 u = __float_as_uint(f);
  hi = bf16_rne(u);
  lo = bf16_rne(__float_as_uint(f - __uint_as_float(hi << 16)));
}
__device__ __forceinline__ float sigmoidf_(float x) { return 1.f / (1.f + __expf(-x)); }
__device__ __forceinline__ float tanhf_(float x) {
  float e = __expf(-2.f * fabsf(x));
  return copysignf((1.f - e) / (1.f + e), x);
}
__device__ __forceinline__ void gl_lds16(const void* g, void* l) {
  __builtin_amdgcn_global_load_lds(
      (const __attribute__((address_space(1))) u32*)(g),
      (__attribute__((address_space(3))) u32*)(l), 16, 0, 0);
}

// ---------------- prep: weight images, K-order (cg, tap, ch8) ----------------
// block idx: L1: (nt*6+cg)*9+tap ; L2: L1BLK + (nt*8+cg)*9+tap. 16KB each:
// [pl2][kg4][qrow128][j8] bf16.  q=nt*128+qrow -> co=gate*128+hid (permuted);
// ci = cg*32+kg*8+j (concat channel); element W[co][ci][tap].
__global__ void prep_kernel(const float* __restrict__ W0, const float* __restrict__ b0,
                            const float* __restrict__ W1, const float* __restrict__ b1,
                            u16* __restrict__ Wi, float* __restrict__ bp) {
  const int total = (L1BLK + L2BLK) * 8192 + 1024;
  for (int idx = blockIdx.x * blockDim.x + threadIdx.x; idx < total;
       idx += gridDim.x * blockDim.x) {
    if (idx < (L1BLK + L2BLK) * 8192) {
      const int blk = idx >> 13, o = idx & 8191;
      int nt, cg, tap, CINL;
      const float* W;
      if (blk < L1BLK) { nt = blk / 54; cg = (blk % 54) / 9; tap = blk % 9; CINL = 192; W = W0; }
      else { const int b2 = blk - L1BLK; nt = b2 / 72; cg = (b2 % 72) / 9; tap = b2 % 9; CINL = 256; W = W1; }
      const int pl = o >> 12, kg = (o >> 10) & 3, qrow = (o >> 3) & 127, j = o & 7;
      const int q = nt * 128 + qrow;
      const int hid = ((q >> 6) << 4) | (q & 15), gate = (q >> 4) & 3;
      const int co = gate * 128 + hid;
      const int ci = cg * 32 + kg * 8 + j;
      const float wv = W[(size_t)co * (CINL * 9) + ci * 9 + tap];
      u32 hi, lo; split2(wv, hi, lo);
      Wi[idx] = (u16)(pl ? lo : hi);
    } else {
      const int e2 = idx - (L1BLK + L2BLK) * 8192;
      const int l = e2 >> 9, q = e2 & 511;
      const int hid = ((q >> 6) << 4) | (q & 15), gate = (q >> 4) & 3;
      bp[e2] = (l == 0 ? b0 : b1)[gate * 128 + hid];
    }
  }
}

// ---------------- fused ConvLSTM step body ----------------
// LDS: A halo dbuf 2 x [pl2][kg4][row224] uint4 = 2 x 28672 B.
template <int LAYER>
__device__ __forceinline__ void step_body(
    uint4* ldsA, int mt, int nt,
    const float* __restrict__ x, int t,
    const u16* __restrict__ P1h, const u16* __restrict__ P1l,
    const u16* __restrict__ P2h, const u16* __restrict__ P2l,
    u16* __restrict__ Wh, u16* __restrict__ Wl,
    const u16* __restrict__ Wimg, const float* __restrict__ bp,
    float* __restrict__ c)
{
  constexpr int CG = (LAYER == 1) ? 6 : 8;
  const int tid = threadIdx.x, lane = tid & 63, w = tid >> 6;
  const int wave_m = (w >> 1) * 64, wave_n = (w & 1) * 64;
  const int kgc = lane >> 4, l15 = lane & 15;

  const int m0 = mt * 128;
  const int b0v = m0 / 225, p0v = m0 - b0v * 225;
  const int r0 = b0v * 289 + (p0v / 15) * 17 + (p0v % 15);   // r(m0) - 18

  // per-lane A fragment byte bases (within one A buffer)
  int aoff[4];
  #pragma unroll
  for (int mb = 0; mb < 4; ++mb) {
    int m = m0 + wave_m + mb * 16 + l15; if (m > 14399) m = 14399;
    const int b = m / 225, p = m - b * 225;
    const int r = b * 289 + (p / 15) * 17 + (p % 15) + 18;
    aoff[mb] = (kgc * AROWS + (r - r0 - 18)) * 16;
  }
  // per-lane B byte offsets within a 16KB image (hi at +0, lo at +8192)
  int boffh[4], boffl[4];
  #pragma unroll
  for (int nb = 0; nb < 4; ++nb) {
    boffh[nb] = (kgc * 128 + wave_n + l15 + nb * 16) * 16;
    boffl[nb] = boffh[nb] + 8192;
  }

  f32x4 acc[4][4];
  #pragma unroll
  for (int i = 0; i < 4; ++i)
    #pragma unroll
    for (int j = 0; j < 4; ++j) acc[i][j] = (f32x4){0.f, 0.f, 0.f, 0.f};

  // ---- staging helpers ----
  auto stageA_h = [&](const u16* __restrict__ Ph, const u16* __restrict__ Pl,
                      int choff, uint4* dst) {
    #pragma unroll
    for (int i = 0; i < 7; ++i) {
      const int chunk = w * 7 + i;
      const int e = chunk * 64 + lane;
      const int pk = e / AROWS, row = e - pk * AROWS;
      const int kg = pk & 3;
      const u16* P = (pk >= 4) ? Pl : Ph;
      const char* src = (const char*)P + ((size_t)(r0 + row) * 128 + choff + kg * 8) * 2;
      gl_lds16(src, (char*)dst + chunk * 1024);
    }
  };
  auto stageA_x = [&](int cg, uint4* dst) {
    for (int tau = tid; tau < 4 * AROWS; tau += 256) {
      const int kg = tau / AROWS, row = tau - kg * AROWS;
      const int rg = r0 + row;
      const int rb = rg / 289, rr = rg - rb * 289;
      const int rh = rr / 17 - 1, rw = rr - (rr / 17) * 17 - 1;
      const bool v = ((unsigned)rh < 15u) && ((unsigned)rw < 15u) && (rb < 64);
      const int p = rh * 15 + rw;
      const float* src = x + (((size_t)rb * NT + t) * NCX + cg * 32 + kg * 8) * NPIX + p;
      u32 hw_[4], lw_[4];
      #pragma unroll
      for (int jj = 0; jj < 4; ++jj) {
        const float f0 = v ? src[(2 * jj) * NPIX] : 0.f;
        const float f1 = v ? src[(2 * jj + 1) * NPIX] : 0.f;
        u32 h0, l0, h1, l1;
        split2(f0, h0, l0); split2(f1, h1, l1);
        hw_[jj] = (h1 << 16) | h0; lw_[jj] = (l1 << 16) | l0;
      }
      dst[kg * AROWS + row]       = make_uint4(hw_[0], hw_[1], hw_[2], hw_[3]);
      dst[(4 + kg) * AROWS + row] = make_uint4(lw_[0], lw_[1], lw_[2], lw_[3]);
    }
  };
  auto stageA = [&](int cg, uint4* dst) {
    if (LAYER == 1) {
      if (cg < 2) stageA_x(cg, dst);
      else        stageA_h(P1h, P1l, (cg - 2) * 32, dst);
    } else {
      if (cg < 4) stageA_h(P1h, P1l, cg * 32, dst);
      else        stageA_h(P2h, P2l, (cg - 4) * 32, dst);
    }
  };

  // ---- main: CG groups; A dbuf in LDS, B dbuf in regs, 1 barrier/cg ----
  stageA(0, ldsA);
  __syncthreads();
  for (int cg = 0; cg < CG; ++cg) {
    const uint4* cbuf = ldsA + (cg & 1) * 1792;
    uint4* nbuf = ldsA + ((cg + 1) & 1) * 1792;
    const char* wb = (const char*)Wimg + (((size_t)(nt * CG + cg) * 9) << 14);

    short8 bh[2][4], bl[2][4];
    #pragma unroll
    for (int nb = 0; nb < 4; ++nb) {
      bh[0][nb] = *(const short8*)(wb + boffh[nb]);
      bl[0][nb] = *(const short8*)(wb + boffl[nb]);
    }
    #pragma unroll
    for (int tap = 0; tap < 9; ++tap) {
      const int cur = tap & 1, nxt = cur ^ 1;
      if (tap < 8) {
        const char* wbn = wb + ((size_t)(tap + 1) << 14);
        #pragma unroll
        for (int nb = 0; nb < 4; ++nb) {
          bh[nxt][nb] = *(const short8*)(wbn + boffh[nb]);
          bl[nxt][nb] = *(const short8*)(wbn + boffl[nb]);
        }
      }
      // issue next cg's A-stage after tap1's B prefetch: FIFO position lets
      // taps 1-2 wait only on B, and the stage drains during taps 2-8.
      if (tap == 1 && cg + 1 < CG) stageA(cg + 1, nbuf);

      const int DPO = ((tap / 3) * 17 + (tap % 3)) * 16;   // tap shift (bytes)
      const char* A = (const char*)cbuf;
      short8 ah[4], al[4];
      #pragma unroll
      for (int mb = 0; mb < 4; ++mb) {
        ah[mb] = *(const short8*)(A + aoff[mb] + DPO);
        al[mb] = *(const short8*)(A + aoff[mb] + DPO + 14336);
      }
      __builtin_amdgcn_s_setprio(1);
      #pragma unroll
      for (int mb = 0; mb < 4; ++mb)
        #pragma unroll
        for (int nb = 0; nb < 4; ++nb) {
          acc[mb][nb] = __builtin_amdgcn_mfma_f32_16x16x32_bf16(ah[mb], bh[cur][nb], acc[mb][nb], 0, 0, 0);
          acc[mb][nb] = __builtin_amdgcn_mfma_f32_16x16x32_bf16(al[mb], bh[cur][nb], acc[mb][nb], 0, 0, 0);
          acc[mb][nb] = __builtin_amdgcn_mfma_f32_16x16x32_bf16(ah[mb], bl[cur][nb], acc[mb][nb], 0, 0, 0);
        }
      __builtin_amdgcn_s_setprio(0);
    }
    __syncthreads();   // my ds_reads done; all stage gl_lds drained -> nbuf ready
  }

  // ---- epilogue: gates -> c/h update; nb index == gate (0=i 1=f 2=o 3=g) ----
  const int colq = nt * 128 + wave_n;
  const int hid  = ((colq >> 6) << 4) + l15;
  const float bi  = bp[colq +      l15];
  const float bf_ = bp[colq + 16 + l15];
  const float bo  = bp[colq + 32 + l15];
  const float bg  = bp[colq + 48 + l15];
  #pragma unroll
  for (int mb = 0; mb < 4; ++mb) {
    #pragma unroll
    for (int rr = 0; rr < 4; ++rr) {
      const int m = m0 + wave_m + mb * 16 + ((lane >> 4) << 2) + rr;
      if (m < MTOT) {
        const float gi = sigmoidf_(acc[mb][0][rr] + bi);
        const float gf = sigmoidf_(acc[mb][1][rr] + bf_);
        const float go = sigmoidf_(acc[mb][2][rr] + bo);
        const float gg = tanhf_   (acc[mb][3][rr] + bg);
        const size_t cidx = (size_t)m * NHID + hid;
        const float cn = gf * c[cidx] + gi * gg;
        c[cidx] = cn;
        const float h = go * tanhf_(cn);
        u32 hh, hl2; split2(h, hh, hl2);
        const int b = m / 225, p = m - b * 225;
        const size_t r = (size_t)b * 289 + (p / 15) * 17 + (p % 15) + 18;
        Wh[r * 128 + hid] = (u16)hh;
        Wl[r * 128 + hid] = (u16)hl2;
      }
    }
  }
}

// z=0 -> L2(t) (if do_l2 else L1), z=1 -> L1(t+1). XCD swizzle at 904 blocks.
__global__ __launch_bounds__(256, 2)
void steps_kernel(const float* __restrict__ x, int t1,
                  const u16* __restrict__ h1hr, const u16* __restrict__ h1lr,
                  const u16* __restrict__ h2hr, const u16* __restrict__ h2lr,
                  u16* __restrict__ h1hw, u16* __restrict__ h1lw,
                  u16* __restrict__ h2hw, u16* __restrict__ h2lw,
                  const u16* __restrict__ Wi, const float* __restrict__ bp,
                  float* __restrict__ c1, float* __restrict__ c2, int do_l2) {
  __shared__ uint4 ldsA[3584];   // 2 x 28672 B
  int bid = ((int)blockIdx.z * 4 + (int)blockIdx.y) * MT_TILES + (int)blockIdx.x;
  int nid = bid;
  if (gridDim.z == 2) nid = (bid & 7) * MT_TILES + (bid >> 3);  // 904 = 8*113
  const int z   = nid / (MT_TILES * 4);
  const int rem = nid - z * (MT_TILES * 4);
  const int nt  = rem / MT_TILES;
  const int mt  = rem - nt * MT_TILES;
  if (z == 0 && do_l2)
    step_body<2>(ldsA, mt, nt, nullptr, 0, h1hr, h1lr, h2hr, h2lr,
                 h2hw, h2lw, Wi + (size_t)L1BLK * 8192, bp + 512, c2);
  else
    step_body<1>(ldsA, mt, nt, x, t1, h1hr, h1lr, nullptr, nullptr,
                 h1hw, h1lw, Wi, bp, c1);
}

// ---------------- final dense: feat[64][28800] @ Wd[28800][128] + bd ----------------
__global__ __launch_bounds__(256)
void dense_kernel(const u16* __restrict__ H2h, const u16* __restrict__ H2l,
                  const float* __restrict__ Wd, float* __restrict__ part) {
  __shared__ float sfeat[1800];
  __shared__ float red[128];
  const int b = blockIdx.x, ks = blockIdx.y, tid = threadIdx.x;
  for (int idx = tid; idx < 1800; idx += 256) {
    const int hid_l = idx & 7, pix = idx >> 3;
    const size_t r = (size_t)b * 289 + (pix / 15) * 17 + (pix % 15) + 18;
    const size_t si = r * 128 + ks * 8 + hid_l;
    sfeat[hid_l * 225 + pix] = bf2f(H2h[si]) + bf2f(H2l[si]);
  }
  __syncthreads();
  const int kk2 = tid >> 7, n = tid & 127;
  const float* wdp = Wd + (size_t)ks * 1800 * 128 + n;
  float s = 0.f;
  #pragma unroll 4
  for (int i = kk2; i < 1800; i += 2)
    s = fmaf(sfeat[i], wdp[(size_t)i * 128], s);
  if (kk2) red[n] = s;
  __syncthreads();
  if (!kk2) part[((size_t)b * 16 + ks) * 128 + n] = s + red[n];
}
__global__ void dense_reduce(const float* __restrict__ part, const float* __restrict__ bd,
                             float* __restrict__ out) {
  const int b = blockIdx.x, n = threadIdx.x;
  float s = bd[n];
  #pragma unroll
  for (int ks = 0; ks < 16; ++ks) s += part[((size_t)b * 16 + ks) * 128 + n];
  out[b * 128 + n] = s;
}

extern "C" void kernel_launch(void* const* d_in, const int* in_sizes, int n_in,
                              void* d_out, int out_size, void* d_ws, size_t ws_size,
                              hipStream_t stream) {
  const float* x  = (const float*)d_in[0];
  const float* W0 = (const float*)d_in[1];
  const float* b0 = (const float*)d_in[2];
  const float* W1 = (const float*)d_in[3];
  const float* b1 = (const float*)d_in[4];
  const float* Wd = (const float*)d_in[5];
  const float* bd = (const float*)d_in[6];

  const size_t HPB = (size_t)RROWS * 128 * 2;   // 4,767,744 B per plane
  const size_t CSZ = (size_t)MTOT * NHID * 4;   // 7,372,800 B
  char* base = (char*)d_ws;
  u16* h1h[2] = { (u16*)(base),            (u16*)(base + HPB) };
  u16* h1l[2] = { (u16*)(base + 2 * HPB),  (u16*)(base + 3 * HPB) };
  u16* h2h[2] = { (u16*)(base + 4 * HPB),  (u16*)(base + 5 * HPB) };
  u16* h2l[2] = { (u16*)(base + 6 * HPB),  (u16*)(base + 7 * HPB) };
  float* c1 = (float*)(base + 8 * HPB);
  float* c2 = (float*)(base + 8 * HPB + CSZ);
  u16* Wi   = (u16*)(base + 8 * HPB + 2 * CSZ);
  const size_t WIB = (size_t)(L1BLK + L2BLK) * 16384;
  float* bp   = (float*)((char*)Wi + WIB);
  float* part = bp + 1024;
  const size_t need = 8 * HPB + 2 * CSZ + WIB + 1024 * 4 + (size_t)64 * 16 * 128 * 4;
  if (ws_size < need) return;

  // zero planes + cells (zero ring of padded planes + initial states)
  hipMemsetAsync(d_ws, 0, 8 * HPB + 2 * CSZ, stream);
  prep_kernel<<<2048, 256, 0, stream>>>(W0, b0, W1, b1, Wi, bp);

  // launch k = -1..47: {L2(k) if k>=0} || {L1(k+1) if k<=46}
  for (int k = -1; k <= 47; ++k) {
    const int rd = k & 1, wr = (k + 1) & 1;
    const int dl2 = (k >= 0), dl1 = (k <= 46);
    dim3 grid(MT_TILES, 4, dl1 + dl2);
    steps_kernel<<<grid, 256, 0, stream>>>(x, k + 1,
        h1h[rd], h1l[rd], h2h[rd], h2l[rd],
        h1h[wr], h1l[wr], h2h[wr], h2l[wr],
        Wi, bp, c1, c2, dl2);
  }
  // final h2(47) in buf 0
  dense_kernel<<<dim3(64, 16), 256, 0, stream>>>(h2h[0], h2l[0], Wd, part);
  dense_reduce<<<64, 128, 0, stream>>>(part, bd, (float*)d_out);
}